// Round 9
// baseline (225.015 us; speedup 1.0000x reference)
//
#include <hip/hip_runtime.h>

// Exact KNN (faiss-equivalent, (dist,idx)-lexicographic ties) + fused neighbor
// feature sum. N=65536 pts on 128^3 int grid, K=16, C=64.
//
// Cells = 4^3 coords -> 32^3 = 32768 cells, ~2 pts/cell. Key = (d2<<16)|idx
// (d2 <= 48387 < 2^16): unsigned order == (dist, idx) lexicographic.
//
// PROLOGUE lessons (r1-r6): no grid barriers (~8us each); no same-address
// atomic multiplicity > ~100 (~100ns/RMW); deterministic cell-ordered layout.
// r9: chunk_reduce fused into scan_chunk (block b reduces counts[0..b*256)
// itself, coalesced; worst block ~2us, runs in parallel) -> one less dispatch.
//
// KNN lessons: r0-r7 pinned at ~42us across configs varying VALU +-50%,
// waves 2x, load width 2x. r8 (LDS-staged per-lane scan) = 82us: lane-
// divergent ds_read chains + 2 blocks/CU occupancy + 417K bank conflicts.
// r9: SPLIT search and gather into two kernels (ablation-as-production):
//  - knn_search (r7 wave structure: 16q x 4 slices, 4-row streams, med3
//    insert, merge tree) writes 16 neighbor ids per query (ushort) to nbr[],
//    indexed by ORIGINAL query idx. Final merge is fully sorted so all 4
//    slices hold identical arrays; slice s stores k[4s..4s+3] as one 8B word.
//  - gather kernel: 1M lanes (q,ch): read nbr (coalesced ushort), 16 shfl +
//    16 float4 row loads + sum, write out[q]. 16 waves/SIMD of tiny-VGPR
//    pure-gather work = max latency hiding for the compulsory 16.8M loads.
// rocprof now times scan vs gather separately -> decides if gather's
// compulsory address stream is the floor.
//
// knn_search scan: quadrant-aligned 4x4x4 cell box, SHIFT-clamped (origin
// clamp [0,28]) -> always full box; uncovered min-d2 >= 49. Cold redo
// (P~1e-7/query): sliced rescan cube r<=2 then Chebyshev shells r>=3
// ((4r-3)^2 bound), exact.

typedef unsigned int uint;
typedef unsigned short ushort;
typedef short short2v __attribute__((ext_vector_type(2)));
typedef uint u32x4 __attribute__((ext_vector_type(4), aligned(8)));

#define NPTS   65536
#define NCELL  32768

static __device__ inline short2v u2s(uint v) { union { uint u; short2v s; } c; c.u = v; return c.s; }
static __device__ inline uint s2u(short2v v) { union { uint u; short2v s; } c; c.s = v; return c.u; }

static __device__ inline int dot2acc(short2v a, short2v b, int c) {
#if __has_builtin(__builtin_amdgcn_sdot2)
    return __builtin_amdgcn_sdot2(a, b, c, false);
#else
    return (int)a.x * (int)b.x + (int)a.y * (int)b.y + c;
#endif
}

__global__ __launch_bounds__(256) void cell_count(const int* __restrict__ coords,
                                                  uint* __restrict__ counts) {
    int i = blockIdx.x * 256 + threadIdx.x;
    int x = coords[3 * i + 0], y = coords[3 * i + 1], z = coords[3 * i + 2];
    int cell = (x >> 2) | ((y >> 2) << 5) | ((z >> 2) << 10);
    atomicAdd(&counts[cell], 1u);
}

// Fused scan: block b computes base = sum(counts[0..b*256)) itself
// (coalesced strided loads, no atomics, no extra dispatch), then block-local
// scan of its 256 cells. Deterministic cell-ordered layout.
__global__ __launch_bounds__(256) void scan_fused(const uint* __restrict__ counts,
                                                  uint* __restrict__ starts,
                                                  uint* __restrict__ cursors) {
    __shared__ uint wsum[4];
    __shared__ uint rsum[4];
    int b = blockIdx.x;
    int tid = threadIdx.x;
    int lane = tid & 63, wv = tid >> 6;
    int cell = b * 256 + tid;

    // ---- base = sum of all counts before this chunk ----
    uint acc = 0;
    int lim = b * 256;
    for (int j = tid; j < lim; j += 256) acc += counts[j];
#pragma unroll
    for (int off = 32; off; off >>= 1) acc += __shfl_xor(acc, off, 64);
    if (lane == 0) rsum[wv] = acc;

    // ---- block-local scan of this chunk's 256 counts ----
    uint c = counts[cell];
    uint v = c;
#pragma unroll
    for (int off = 1; off < 64; off <<= 1) {
        uint u = __shfl_up(v, off, 64);
        if (lane >= off) v += u;
    }
    if (lane == 63) wsum[wv] = v;
    __syncthreads();
    uint base = rsum[0] + rsum[1] + rsum[2] + rsum[3];
    uint woff = 0;
#pragma unroll
    for (int j = 0; j < 4; ++j) woff += (j < wv) ? wsum[j] : 0u;
    uint st = base + woff + v - c;
    starts[cell]  = st;
    cursors[cell] = st;
    if (cell == NCELL - 1) starts[NCELL] = st + c;   // = 65536
}

__global__ __launch_bounds__(256) void cell_scatter(const int* __restrict__ coords,
                                                    uint* __restrict__ cursors,
                                                    uint2* __restrict__ sorted) {
    int i = blockIdx.x * 256 + threadIdx.x;
    int x = coords[3 * i + 0], y = coords[3 * i + 1], z = coords[3 * i + 2];
    int cell = (x >> 2) | ((y >> 2) << 5) | ((z >> 2) << 10);
    uint pos = atomicAdd(&cursors[cell], 1u);
    // packed: w0 = x | y<<16, w1 = idx | z<<16
    sorted[pos] = make_uint2((uint)(x | (y << 16)), (uint)(i | (z << 16)));
}

__global__ __launch_bounds__(256, 4) void knn_search(const uint* __restrict__ starts,
                                                     const uint2* __restrict__ sorted,
                                                     uint2* __restrict__ nbr) {
    // XCD-chunked swizzle: consecutive logical blocks -> same XCD L2.
    int blk  = (blockIdx.x & 7) * 128 + (blockIdx.x >> 3);   // 1024 blocks
    int wave = threadIdx.x >> 6;                             // 4 waves/block
    int lane = threadIdx.x & 63;
    int qslot = lane & 15;                                   // 16 queries/wave
    int slice = lane >> 4;                                   // 4 slices/query
    int qpos = blk * 64 + wave * 16 + qslot;

    uint2 me = sorted[qpos];
    uint qxy = me.x;                       // qx | qy<<16
    uint qzp = me.y & 0xFFFF0000u;         // qz<<16
    uint qidx = me.y & 0xFFFFu;            // original index
    int qx = (int)(me.x & 0xFFFFu);
    int qy = (int)(me.x >> 16);
    int qz = (int)(me.y >> 16);
    int cx = qx >> 2, cy = qy >> 2, cz = qz >> 2;

    uint k[16];
#pragma unroll
    for (int j = 0; j < 16; ++j) k[j] = 0xFFFFFFFFu;

    auto insert1 = [&](uint2 pt) {
        short2v A = u2s(pt.x) - u2s(qxy);          // (dx, dy)
        short2v B = u2s(pt.y) - u2s(qzp);          // (idx, dz)
        uint Bu = s2u(B);
        short2v Bm = u2s(Bu & 0xFFFF0000u);        // (0, dz)
        int d2 = dot2acc(A, A, dot2acc(Bm, Bm, 0));
        uint key = ((uint)d2 << 16) + (Bu & 0xFFFFu);
#pragma unroll
        for (int j = 15; j >= 1; --j)
            asm("v_med3_u32 %0, %1, %2, %3"
                : "=v"(k[j]) : "v"(k[j - 1]), "v"(k[j]), "v"(key));
        k[0] = min(k[0], key);
    };

    // sliced scan (stride 4 across slices) -- used only by the cold redo path
    auto scan4 = [&](uint p0, uint p1) {
        for (uint p = p0 + (uint)slice; p < p1; p += 4u) insert1(sorted[p]);
    };

    auto merge_min = [&](int mask) {
        uint b[16];
#pragma unroll
        for (int j = 0; j < 16; ++j) b[j] = __shfl_xor(k[j], mask, 64);
#pragma unroll
        for (int j = 0; j < 16; ++j) k[j] = min(k[j], b[15 - j]);
    };
    auto clean = [&]() {
#pragma unroll
        for (int d = 8; d >= 1; d >>= 1) {
#pragma unroll
            for (int i = 0; i < 16; ++i) {
                if ((i & d) == 0) {
                    uint lo = min(k[i], k[i + d]);
                    uint hi = max(k[i], k[i + d]);
                    k[i] = lo;
                    k[i + d] = hi;
                }
            }
        }
    };
    auto merge = [&](int mask) { merge_min(mask); clean(); };
    // full merges: all 4 slices end with IDENTICAL sorted arrays (required
    // by the cooperative nbr write below)
    auto merge_all = [&]() { merge(16); merge(32); };

    // ---- quadrant-aligned 4x4x4 box, SHIFT-clamped (always full size) ----
    int xa = min(max(cx - ((qx & 3) < 2 ? 2 : 1), 0), 28);
    int ya = min(max(cy - ((qy & 3) < 2 ? 2 : 1), 0), 28);
    int za = min(max(cz - ((qz & 3) < 2 ? 2 : 1), 0), 28);

    // lane owns 4 whole rows: y = ya+slice, z = za+0..3. 4 streams, 2 pts
    // per stream per iteration via ONE 16-B load (pad entry in 'sorted'
    // keeps the tail read in-bounds; inserts predicated).
    {
        int ybase = (ya + slice) << 5;
        int rb0 = ybase | ((za + 0) << 10);
        int rb1 = ybase | ((za + 1) << 10);
        int rb2 = ybase | ((za + 2) << 10);
        int rb3 = ybase | ((za + 3) << 10);
        uint pA = starts[rb0 + xa], eA = starts[rb0 + xa + 4];
        uint pB = starts[rb1 + xa], eB = starts[rb1 + xa + 4];
        uint pC = starts[rb2 + xa], eC = starts[rb2 + xa + 4];
        uint pD = starts[rb3 + xa], eD = starts[rb3 + xa + 4];
        while (__any((pA < eA) || (pB < eB) || (pC < eC) || (pD < eD))) {
            bool a0 = pA < eA, a1 = pA + 1 < eA;
            bool b0 = pB < eB, b1 = pB + 1 < eB;
            bool c0 = pC < eC, c1 = pC + 1 < eC;
            bool d0 = pD < eD, d1 = pD + 1 < eD;
            u32x4 VA, VB, VC, VD;
            if (a0) VA = *reinterpret_cast<const u32x4*>(sorted + pA);
            if (b0) VB = *reinterpret_cast<const u32x4*>(sorted + pB);
            if (c0) VC = *reinterpret_cast<const u32x4*>(sorted + pC);
            if (d0) VD = *reinterpret_cast<const u32x4*>(sorted + pD);
            pA += (a0 ? 1u : 0u) + (a1 ? 1u : 0u);
            pB += (b0 ? 1u : 0u) + (b1 ? 1u : 0u);
            pC += (c0 ? 1u : 0u) + (c1 ? 1u : 0u);
            pD += (d0 ? 1u : 0u) + (d1 ? 1u : 0u);
            if (a0) insert1(make_uint2(VA.x, VA.y));
            if (b0) insert1(make_uint2(VB.x, VB.y));
            if (c0) insert1(make_uint2(VC.x, VC.y));
            if (d0) insert1(make_uint2(VD.x, VD.y));
            if (a1) insert1(make_uint2(VA.z, VA.w));
            if (b1) insert1(make_uint2(VB.z, VB.w));
            if (c1) insert1(make_uint2(VC.z, VC.w));
            if (d1) insert1(make_uint2(VD.z, VD.w));
        }
    }
    merge_all();   // exact sorted top-16, identical in all 4 slices

    // ---- cold redo: uncovered space has min-d2 >= 49 (P ~ 1e-7/query) ----
    bool redo = (k[15] >> 16) >= 49u;
    if (__any(redo)) {
        // triggered queries: discard everything, rescan from scratch (sliced).
        // others: keep slice 0 only (slices!=0 must reset before re-merge).
        if (redo || slice != 0) {
#pragma unroll
            for (int j = 0; j < 16; ++j) k[j] = 0xFFFFFFFFu;
        }
        if (redo) {
            int xl = max(cx - 2, 0), xh = min(cx + 2, 31);
            int yl = max(cy - 2, 0), yh = min(cy + 2, 31);
            int zl = max(cz - 2, 0), zh = min(cz + 2, 31);
            for (int z = zl; z <= zh; ++z)
                for (int y = yl; y <= yh; ++y) {
                    int rb = (y << 5) | (z << 10);
                    scan4(starts[rb + xl], starts[rb + xh + 1]);
                }
        }
        merge_all();
        for (int r = 3; r < 32; ++r) {
            uint b = (uint)(4 * r - 3);
            bool active = (k[15] >> 16) >= b * b;
            if (!__any(active)) break;
            if (slice != 0) {
#pragma unroll
                for (int j = 0; j < 16; ++j) k[j] = 0xFFFFFFFFu;
            }
            if (active) {
                int z0 = cz - r < 0 ? 0 : cz - r;
                int z1 = cz + r > 31 ? 31 : cz + r;
                for (int z = z0; z <= z1; ++z) {
                    bool zface = (z == cz - r) || (z == cz + r);
                    int y0 = cy - r < 0 ? 0 : cy - r;
                    int y1 = cy + r > 31 ? 31 : cy + r;
                    for (int y = y0; y <= y1; ++y) {
                        bool face = zface || (y == cy - r) || (y == cy + r);
                        int rb = (y << 5) | (z << 10);
                        if (face) {
                            int x0 = cx - r < 0 ? 0 : cx - r;
                            int x1 = cx + r > 31 ? 31 : cx + r;
                            scan4(starts[rb + x0], starts[rb + x1 + 1]);
                        } else {
                            int xL = cx - r;
                            if (xL >= 0) scan4(starts[rb + xL], starts[rb + xL + 1]);
                            int xR = cx + r;
                            if (xR <= 31) scan4(starts[rb + xR], starts[rb + xR + 1]);
                        }
                    }
                }
            }
            merge_all();
        }
    }

    // ---- write neighbor ids: slice s stores k[4s..4s+3] (arrays identical
    //      across slices after full merge) as one 8B word, row = qidx ----
    int s4 = slice * 4;
    uint w0 = (k[s4 + 0] & 0xFFFFu) | (k[s4 + 1] << 16);
    uint w1 = (k[s4 + 2] & 0xFFFFu) | (k[s4 + 3] << 16);
    nbr[qidx * 4u + (uint)slice] = make_uint2(w0, w1);
}

// Dedicated gather: 1M lanes, lane = (query, channel-quad). Tiny VGPR, 16
// waves/SIMD -> deep latency hiding for the compulsory feature-row loads.
__global__ __launch_bounds__(256) void gather(const ushort* __restrict__ nbr,
                                              const float* __restrict__ feat,
                                              float* __restrict__ out) {
    int g = blockIdx.x * 256 + threadIdx.x;
    int q = g >> 4, ch = g & 15;
    int lane = threadIdx.x & 63;
    uint nv = nbr[q * 16 + ch];            // coalesced: 128B per wave
    float4 acc = make_float4(0.f, 0.f, 0.f, 0.f);
#pragma unroll
    for (int j = 0; j < 16; ++j) {
        uint nj = __shfl(nv, (lane & 48) + j, 64);
        float4 v = reinterpret_cast<const float4*>(feat)[nj * 16u + (uint)ch];
        acc.x += v.x; acc.y += v.y; acc.z += v.z; acc.w += v.w;
    }
    reinterpret_cast<float4*>(out)[(uint)q * 16u + (uint)ch] = acc;
}

extern "C" void kernel_launch(void* const* d_in, const int* in_sizes, int n_in,
                              void* d_out, int out_size, void* d_ws, size_t ws_size,
                              hipStream_t stream) {
    const int*   coords = (const int*)d_in[0];
    const float* feat   = (const float*)d_in[1];
    float*       out    = (float*)d_out;

    uint* W = (uint*)d_ws;
    uint*  counts  = W;                       // 32768, memset-zeroed
    uint*  starts  = W + 32768;               // 32769
    uint*  cursors = W + 65540;               // 32768 (16B aligned)
    uint2* sorted  = (uint2*)(W + 98308);     // 65536 entries + 1 pad (16B reads)
    uint2* nbr     = (uint2*)(W + 229384);    // 65536 * 16 ushort = 2MB (8B aligned)

    hipMemsetAsync(counts, 0, NCELL * sizeof(uint), stream);
    cell_count<<<NPTS / 256, 256, 0, stream>>>(coords, counts);
    scan_fused<<<NCELL / 256, 256, 0, stream>>>(counts, starts, cursors);
    cell_scatter<<<NPTS / 256, 256, 0, stream>>>(coords, cursors, sorted);
    knn_search<<<1024, 256, 0, stream>>>(starts, sorted, nbr);
    gather<<<NPTS * 16 / 256, 256, 0, stream>>>((const ushort*)nbr, feat, out);
}

// Round 10
// 97.777 us; speedup vs baseline: 2.3013x; 2.3013x over previous
//
#include <hip/hip_runtime.h>

// Exact KNN (faiss-equivalent, (dist,idx)-lexicographic ties) + fused neighbor
// feature sum. N=65536 pts on 128^3 int grid, K=16, C=64.
//
// Cells = 4^3 coords -> 32^3 = 32768 cells, ~2 pts/cell. Key = (d2<<16)|idx
// (d2 <= 48387 < 2^16): unsigned order == (dist, idx) lexicographic.
//
// PROLOGUE lessons (r1-r6): no grid barriers (~8us each); no same-address
// atomic multiplicity > ~100 (~100ns/RMW); deterministic cell-ordered layout;
// scan fused into one dispatch (block b self-reduces counts[0..b*256)).
//
// KNN lessons:
//  r0-r7: fused kernel pinned ~42us across configs varying VALU +-50%,
//         waves 2x, load width 2x -> consistent with VMEM lane-address
//         throughput ~1 addr/cyc/CU (scan 4.2M + gather 16.8M + stores 1M
//         ~= 34us floor).
//  r8:    LDS-staged per-lane scan = 82us (divergent ds chains, 2 blk/CU).
//  r9:    RULE #20 VIOLATION: nbr write indexed k[slice*4+j] with runtime
//         slice*4 -> compiler promoted k[16] to LDS (LDS_Block_Size=16384,
//         6.1e7 bank conflicts, 161us). Private arrays must be indexed with
//         compile-time constants ONLY.
//  r10:   fix = pack all 8 half-words with constant indices, select the
//         slice's pair via a value-select chain. Search/gather split kept:
//         rocprof times scan+sort vs gather separately (the ablation that
//         decides whether gather's compulsory 16.8M addresses are the floor).
//
// knn_search scan: quadrant-aligned 4x4x4 cell box, SHIFT-clamped (origin
// clamp [0,28]) -> always full box; uncovered min-d2 >= 49. Wave = 16
// queries x 4 slices; lane owns 4 rows (y=ya+slice, z=za+0..3), 2 pts/iter
// per row stream via one 16-B load. med3 insert network; full merge tree
// (masks 16,32) so all 4 slices end with identical sorted top-16. Cold redo
// (P~1e-7/query): sliced rescan cube r<=2 then Chebyshev shells r>=3
// ((4r-3)^2 bound), exact.
// gather: 1M lanes (q, ch-quad); 16 coalesced ushort nbr reads per 16-lane
// group, 16 shfl + 16 float4 row loads + sum; tiny VGPR -> deep occupancy.

typedef unsigned int uint;
typedef unsigned short ushort;
typedef short short2v __attribute__((ext_vector_type(2)));
typedef uint u32x4 __attribute__((ext_vector_type(4), aligned(8)));

#define NPTS   65536
#define NCELL  32768

static __device__ inline short2v u2s(uint v) { union { uint u; short2v s; } c; c.u = v; return c.s; }
static __device__ inline uint s2u(short2v v) { union { uint u; short2v s; } c; c.s = v; return c.u; }

static __device__ inline int dot2acc(short2v a, short2v b, int c) {
#if __has_builtin(__builtin_amdgcn_sdot2)
    return __builtin_amdgcn_sdot2(a, b, c, false);
#else
    return (int)a.x * (int)b.x + (int)a.y * (int)b.y + c;
#endif
}

__global__ __launch_bounds__(256) void cell_count(const int* __restrict__ coords,
                                                  uint* __restrict__ counts) {
    int i = blockIdx.x * 256 + threadIdx.x;
    int x = coords[3 * i + 0], y = coords[3 * i + 1], z = coords[3 * i + 2];
    int cell = (x >> 2) | ((y >> 2) << 5) | ((z >> 2) << 10);
    atomicAdd(&counts[cell], 1u);
}

// Fused scan: block b computes base = sum(counts[0..b*256)) itself
// (coalesced strided loads, no atomics), then block-local scan of 256 cells.
__global__ __launch_bounds__(256) void scan_fused(const uint* __restrict__ counts,
                                                  uint* __restrict__ starts,
                                                  uint* __restrict__ cursors) {
    __shared__ uint wsum[4];
    __shared__ uint rsum[4];
    int b = blockIdx.x;
    int tid = threadIdx.x;
    int lane = tid & 63, wv = tid >> 6;
    int cell = b * 256 + tid;

    uint acc = 0;
    int lim = b * 256;
    for (int j = tid; j < lim; j += 256) acc += counts[j];
#pragma unroll
    for (int off = 32; off; off >>= 1) acc += __shfl_xor(acc, off, 64);
    if (lane == 0) rsum[wv] = acc;

    uint c = counts[cell];
    uint v = c;
#pragma unroll
    for (int off = 1; off < 64; off <<= 1) {
        uint u = __shfl_up(v, off, 64);
        if (lane >= off) v += u;
    }
    if (lane == 63) wsum[wv] = v;
    __syncthreads();
    uint base = rsum[0] + rsum[1] + rsum[2] + rsum[3];
    uint woff = 0;
#pragma unroll
    for (int j = 0; j < 4; ++j) woff += (j < wv) ? wsum[j] : 0u;
    uint st = base + woff + v - c;
    starts[cell]  = st;
    cursors[cell] = st;
    if (cell == NCELL - 1) starts[NCELL] = st + c;   // = 65536
}

__global__ __launch_bounds__(256) void cell_scatter(const int* __restrict__ coords,
                                                    uint* __restrict__ cursors,
                                                    uint2* __restrict__ sorted) {
    int i = blockIdx.x * 256 + threadIdx.x;
    int x = coords[3 * i + 0], y = coords[3 * i + 1], z = coords[3 * i + 2];
    int cell = (x >> 2) | ((y >> 2) << 5) | ((z >> 2) << 10);
    uint pos = atomicAdd(&cursors[cell], 1u);
    // packed: w0 = x | y<<16, w1 = idx | z<<16
    sorted[pos] = make_uint2((uint)(x | (y << 16)), (uint)(i | (z << 16)));
}

__global__ __launch_bounds__(256, 4) void knn_search(const uint* __restrict__ starts,
                                                     const uint2* __restrict__ sorted,
                                                     uint2* __restrict__ nbr) {
    // XCD-chunked swizzle: consecutive logical blocks -> same XCD L2.
    int blk  = (blockIdx.x & 7) * 128 + (blockIdx.x >> 3);   // 1024 blocks
    int wave = threadIdx.x >> 6;                             // 4 waves/block
    int lane = threadIdx.x & 63;
    int qslot = lane & 15;                                   // 16 queries/wave
    int slice = lane >> 4;                                   // 4 slices/query
    int qpos = blk * 64 + wave * 16 + qslot;

    uint2 me = sorted[qpos];
    uint qxy = me.x;                       // qx | qy<<16
    uint qzp = me.y & 0xFFFF0000u;         // qz<<16
    uint qidx = me.y & 0xFFFFu;            // original index
    int qx = (int)(me.x & 0xFFFFu);
    int qy = (int)(me.x >> 16);
    int qz = (int)(me.y >> 16);
    int cx = qx >> 2, cy = qy >> 2, cz = qz >> 2;

    uint k[16];
#pragma unroll
    for (int j = 0; j < 16; ++j) k[j] = 0xFFFFFFFFu;

    auto insert1 = [&](uint2 pt) {
        short2v A = u2s(pt.x) - u2s(qxy);          // (dx, dy)
        short2v B = u2s(pt.y) - u2s(qzp);          // (idx, dz)
        uint Bu = s2u(B);
        short2v Bm = u2s(Bu & 0xFFFF0000u);        // (0, dz)
        int d2 = dot2acc(A, A, dot2acc(Bm, Bm, 0));
        uint key = ((uint)d2 << 16) + (Bu & 0xFFFFu);
#pragma unroll
        for (int j = 15; j >= 1; --j)
            asm("v_med3_u32 %0, %1, %2, %3"
                : "=v"(k[j]) : "v"(k[j - 1]), "v"(k[j]), "v"(key));
        k[0] = min(k[0], key);
    };

    // sliced scan (stride 4 across slices) -- used only by the cold redo path
    auto scan4 = [&](uint p0, uint p1) {
        for (uint p = p0 + (uint)slice; p < p1; p += 4u) insert1(sorted[p]);
    };

    auto merge_min = [&](int mask) {
        uint b[16];
#pragma unroll
        for (int j = 0; j < 16; ++j) b[j] = __shfl_xor(k[j], mask, 64);
#pragma unroll
        for (int j = 0; j < 16; ++j) k[j] = min(k[j], b[15 - j]);
    };
    auto clean = [&]() {
#pragma unroll
        for (int d = 8; d >= 1; d >>= 1) {
#pragma unroll
            for (int i = 0; i < 16; ++i) {
                if ((i & d) == 0) {
                    uint lo = min(k[i], k[i + d]);
                    uint hi = max(k[i], k[i + d]);
                    k[i] = lo;
                    k[i + d] = hi;
                }
            }
        }
    };
    auto merge = [&](int mask) { merge_min(mask); clean(); };
    // full merges: all 4 slices end with IDENTICAL sorted arrays (required
    // by the cooperative nbr write below)
    auto merge_all = [&]() { merge(16); merge(32); };

    // ---- quadrant-aligned 4x4x4 box, SHIFT-clamped (always full size) ----
    int xa = min(max(cx - ((qx & 3) < 2 ? 2 : 1), 0), 28);
    int ya = min(max(cy - ((qy & 3) < 2 ? 2 : 1), 0), 28);
    int za = min(max(cz - ((qz & 3) < 2 ? 2 : 1), 0), 28);

    // lane owns 4 whole rows: y = ya+slice, z = za+0..3. 4 streams, 2 pts
    // per stream per iteration via ONE 16-B load (pad entry in 'sorted'
    // keeps the tail read in-bounds; inserts predicated).
    {
        int ybase = (ya + slice) << 5;
        int rb0 = ybase | ((za + 0) << 10);
        int rb1 = ybase | ((za + 1) << 10);
        int rb2 = ybase | ((za + 2) << 10);
        int rb3 = ybase | ((za + 3) << 10);
        uint pA = starts[rb0 + xa], eA = starts[rb0 + xa + 4];
        uint pB = starts[rb1 + xa], eB = starts[rb1 + xa + 4];
        uint pC = starts[rb2 + xa], eC = starts[rb2 + xa + 4];
        uint pD = starts[rb3 + xa], eD = starts[rb3 + xa + 4];
        while (__any((pA < eA) || (pB < eB) || (pC < eC) || (pD < eD))) {
            bool a0 = pA < eA, a1 = pA + 1 < eA;
            bool b0 = pB < eB, b1 = pB + 1 < eB;
            bool c0 = pC < eC, c1 = pC + 1 < eC;
            bool d0 = pD < eD, d1 = pD + 1 < eD;
            u32x4 VA, VB, VC, VD;
            if (a0) VA = *reinterpret_cast<const u32x4*>(sorted + pA);
            if (b0) VB = *reinterpret_cast<const u32x4*>(sorted + pB);
            if (c0) VC = *reinterpret_cast<const u32x4*>(sorted + pC);
            if (d0) VD = *reinterpret_cast<const u32x4*>(sorted + pD);
            pA += (a0 ? 1u : 0u) + (a1 ? 1u : 0u);
            pB += (b0 ? 1u : 0u) + (b1 ? 1u : 0u);
            pC += (c0 ? 1u : 0u) + (c1 ? 1u : 0u);
            pD += (d0 ? 1u : 0u) + (d1 ? 1u : 0u);
            if (a0) insert1(make_uint2(VA.x, VA.y));
            if (b0) insert1(make_uint2(VB.x, VB.y));
            if (c0) insert1(make_uint2(VC.x, VC.y));
            if (d0) insert1(make_uint2(VD.x, VD.y));
            if (a1) insert1(make_uint2(VA.z, VA.w));
            if (b1) insert1(make_uint2(VB.z, VB.w));
            if (c1) insert1(make_uint2(VC.z, VC.w));
            if (d1) insert1(make_uint2(VD.z, VD.w));
        }
    }
    merge_all();   // exact sorted top-16, identical in all 4 slices

    // ---- cold redo: uncovered space has min-d2 >= 49 (P ~ 1e-7/query) ----
    bool redo = (k[15] >> 16) >= 49u;
    if (__any(redo)) {
        // triggered queries: discard everything, rescan from scratch (sliced).
        // others: keep slice 0 only (slices!=0 must reset before re-merge).
        if (redo || slice != 0) {
#pragma unroll
            for (int j = 0; j < 16; ++j) k[j] = 0xFFFFFFFFu;
        }
        if (redo) {
            int xl = max(cx - 2, 0), xh = min(cx + 2, 31);
            int yl = max(cy - 2, 0), yh = min(cy + 2, 31);
            int zl = max(cz - 2, 0), zh = min(cz + 2, 31);
            for (int z = zl; z <= zh; ++z)
                for (int y = yl; y <= yh; ++y) {
                    int rb = (y << 5) | (z << 10);
                    scan4(starts[rb + xl], starts[rb + xh + 1]);
                }
        }
        merge_all();
        for (int r = 3; r < 32; ++r) {
            uint b = (uint)(4 * r - 3);
            bool active = (k[15] >> 16) >= b * b;
            if (!__any(active)) break;
            if (slice != 0) {
#pragma unroll
                for (int j = 0; j < 16; ++j) k[j] = 0xFFFFFFFFu;
            }
            if (active) {
                int z0 = cz - r < 0 ? 0 : cz - r;
                int z1 = cz + r > 31 ? 31 : cz + r;
                for (int z = z0; z <= z1; ++z) {
                    bool zface = (z == cz - r) || (z == cz + r);
                    int y0 = cy - r < 0 ? 0 : cy - r;
                    int y1 = cy + r > 31 ? 31 : cy + r;
                    for (int y = y0; y <= y1; ++y) {
                        bool face = zface || (y == cy - r) || (y == cy + r);
                        int rb = (y << 5) | (z << 10);
                        if (face) {
                            int x0 = cx - r < 0 ? 0 : cx - r;
                            int x1 = cx + r > 31 ? 31 : cx + r;
                            scan4(starts[rb + x0], starts[rb + x1 + 1]);
                        } else {
                            int xL = cx - r;
                            if (xL >= 0) scan4(starts[rb + xL], starts[rb + xL + 1]);
                            int xR = cx + r;
                            if (xR <= 31) scan4(starts[rb + xR], starts[rb + xR + 1]);
                        }
                    }
                }
            }
            merge_all();
        }
    }

    // ---- write neighbor ids: slice s stores k[4s..4s+3] as one 8B word.
    // RULE #20: k[] must be indexed with COMPILE-TIME constants only (r9:
    // runtime k[slice*4+j] demoted k to LDS, 4x slowdown). Pack all 8
    // half-words with constant indices, then value-select by slice.
    uint p0 = (k[0]  & 0xFFFFu) | (k[1]  << 16);
    uint p1 = (k[2]  & 0xFFFFu) | (k[3]  << 16);
    uint p2 = (k[4]  & 0xFFFFu) | (k[5]  << 16);
    uint p3 = (k[6]  & 0xFFFFu) | (k[7]  << 16);
    uint p4 = (k[8]  & 0xFFFFu) | (k[9]  << 16);
    uint p5 = (k[10] & 0xFFFFu) | (k[11] << 16);
    uint p6 = (k[12] & 0xFFFFu) | (k[13] << 16);
    uint p7 = (k[14] & 0xFFFFu) | (k[15] << 16);
    uint w0 = slice == 0 ? p0 : slice == 1 ? p2 : slice == 2 ? p4 : p6;
    uint w1 = slice == 0 ? p1 : slice == 1 ? p3 : slice == 2 ? p5 : p7;
    nbr[qidx * 4u + (uint)slice] = make_uint2(w0, w1);
}

// Dedicated gather: 1M lanes, lane = (query, channel-quad). Tiny VGPR, deep
// occupancy -> max latency hiding for the compulsory feature-row loads.
__global__ __launch_bounds__(256) void gather(const ushort* __restrict__ nbr,
                                              const float* __restrict__ feat,
                                              float* __restrict__ out) {
    int g = blockIdx.x * 256 + threadIdx.x;
    int q = g >> 4, ch = g & 15;
    int lane = threadIdx.x & 63;
    uint nv = nbr[q * 16 + ch];            // coalesced: lane holds nbr[ch]
    float4 acc = make_float4(0.f, 0.f, 0.f, 0.f);
#pragma unroll
    for (int j = 0; j < 16; ++j) {
        uint nj = __shfl(nv, (lane & 48) + j, 64);
        float4 v = reinterpret_cast<const float4*>(feat)[nj * 16u + (uint)ch];
        acc.x += v.x; acc.y += v.y; acc.z += v.z; acc.w += v.w;
    }
    reinterpret_cast<float4*>(out)[(uint)q * 16u + (uint)ch] = acc;
}

extern "C" void kernel_launch(void* const* d_in, const int* in_sizes, int n_in,
                              void* d_out, int out_size, void* d_ws, size_t ws_size,
                              hipStream_t stream) {
    const int*   coords = (const int*)d_in[0];
    const float* feat   = (const float*)d_in[1];
    float*       out    = (float*)d_out;

    uint* W = (uint*)d_ws;
    uint*  counts  = W;                       // 32768, memset-zeroed
    uint*  starts  = W + 32768;               // 32769
    uint*  cursors = W + 65540;               // 32768 (16B aligned)
    uint2* sorted  = (uint2*)(W + 98308);     // 65536 entries + 1 pad (16B reads)
    uint2* nbr     = (uint2*)(W + 229384);    // 65536 * 16 ushort = 2MB (8B aligned)

    hipMemsetAsync(counts, 0, NCELL * sizeof(uint), stream);
    cell_count<<<NPTS / 256, 256, 0, stream>>>(coords, counts);
    scan_fused<<<NCELL / 256, 256, 0, stream>>>(counts, starts, cursors);
    cell_scatter<<<NPTS / 256, 256, 0, stream>>>(coords, cursors, sorted);
    knn_search<<<1024, 256, 0, stream>>>(starts, sorted, nbr);
    gather<<<NPTS * 16 / 256, 256, 0, stream>>>((const ushort*)nbr, feat, out);
}

// Round 11
// 74.761 us; speedup vs baseline: 3.0098x; 1.3079x over previous
//
#include <hip/hip_runtime.h>

// Exact KNN (faiss-equivalent, (dist,idx)-lexicographic ties) + fused neighbor
// feature sum. N=65536 pts on 128^3 int grid, K=16, C=64.
//
// Cells = 4^3 coords -> 32^3 = 32768 cells, ~2 pts/cell. Key = (d2<<16)|idx
// (d2 <= 48387 < 2^16): unsigned order == (dist, idx) lexicographic.
//
// PROLOGUE lessons (r1-r6,r9): no grid barriers (~8us each on MI355X, any
// poll discipline); no same-address atomic multiplicity > ~100 (~100ns/RMW);
// deterministic cell-ordered layout; scan in ONE dispatch (block b
// self-reduces counts[0..b*256), coalesced, no atomics).
//
// KNN lessons (r0-r10):
//  - fused kernel pinned ~42us across configs varying VALU +-50%, waves 2x,
//    load width 2x: consistent with VMEM lane-address throughput ~1/cyc/CU
//    (scan ~4.2M + gather 16.8M + stores ~1M addrs; scan & gather waves
//    OVERLAP inside the fused kernel -> ~max, not sum).
//  - r8 LDS-staged per-lane scan: 82us (divergent ds chains, 2 blk/CU).
//  - r9 RULE #20: runtime-indexed private k[] -> demoted to LDS, 161us.
//    Private arrays: compile-time indices only.
//  - r10 search/gather split: both kernels individually <40us but total
//    97.8us -- splitting destroys the free scan/gather overlap. KEEP FUSED.
// This version = r7 fused knn (best measured: 61.5us total) + scan_fused.
//
// knn_search: wave = 16 queries x 4 slices; lane owns 4 whole rows
// (y = ya+slice, z = za+0..3); 4 streams x 2 pts/iter (one 16-B load each).
// Main scan = quadrant-aligned 4x4x4 cell box, SHIFT-clamped to the grid
// (origin clamp [0,28]) so the box is always full 4x4x4. Guarantee:
// uncovered min-d2 >= 49. Per-lane sorted top-16 via med3 insert network
// (insert order irrelevant: top-k set). Merge tree depth 2 (masks 16,32);
// FINAL merge keeps only the min-half (bitonic, unsorted) since the gather
// is a set-sum; redo bound via max-tree; cold redo path (P~1e-7/query)
// re-sorts first, then full redo: r<=2 cube, then Chebyshev shells r>=3
// (shell-r min-d2 = (4r-3)^2).
// Gather fused: lane = 4 channels x 16 lanes/query, 4 passes x 4 queries;
// float4 feature-row loads; output written directly.

typedef unsigned int uint;
typedef unsigned short ushort;
typedef short short2v __attribute__((ext_vector_type(2)));
typedef uint u32x4 __attribute__((ext_vector_type(4), aligned(8)));

#define NPTS   65536
#define NCELL  32768

static __device__ inline short2v u2s(uint v) { union { uint u; short2v s; } c; c.u = v; return c.s; }
static __device__ inline uint s2u(short2v v) { union { uint u; short2v s; } c; c.s = v; return c.u; }

static __device__ inline int dot2acc(short2v a, short2v b, int c) {
#if __has_builtin(__builtin_amdgcn_sdot2)
    return __builtin_amdgcn_sdot2(a, b, c, false);
#else
    return (int)a.x * (int)b.x + (int)a.y * (int)b.y + c;
#endif
}

__global__ __launch_bounds__(256) void cell_count(const int* __restrict__ coords,
                                                  uint* __restrict__ counts) {
    int i = blockIdx.x * 256 + threadIdx.x;
    int x = coords[3 * i + 0], y = coords[3 * i + 1], z = coords[3 * i + 2];
    int cell = (x >> 2) | ((y >> 2) << 5) | ((z >> 2) << 10);
    atomicAdd(&counts[cell], 1u);
}

// Fused scan: block b computes base = sum(counts[0..b*256)) itself
// (coalesced strided loads, no atomics), then block-local scan of 256 cells.
__global__ __launch_bounds__(256) void scan_fused(const uint* __restrict__ counts,
                                                  uint* __restrict__ starts,
                                                  uint* __restrict__ cursors) {
    __shared__ uint wsum[4];
    __shared__ uint rsum[4];
    int b = blockIdx.x;
    int tid = threadIdx.x;
    int lane = tid & 63, wv = tid >> 6;
    int cell = b * 256 + tid;

    uint acc = 0;
    int lim = b * 256;
    for (int j = tid; j < lim; j += 256) acc += counts[j];
#pragma unroll
    for (int off = 32; off; off >>= 1) acc += __shfl_xor(acc, off, 64);
    if (lane == 0) rsum[wv] = acc;

    uint c = counts[cell];
    uint v = c;
#pragma unroll
    for (int off = 1; off < 64; off <<= 1) {
        uint u = __shfl_up(v, off, 64);
        if (lane >= off) v += u;
    }
    if (lane == 63) wsum[wv] = v;
    __syncthreads();
    uint base = rsum[0] + rsum[1] + rsum[2] + rsum[3];
    uint woff = 0;
#pragma unroll
    for (int j = 0; j < 4; ++j) woff += (j < wv) ? wsum[j] : 0u;
    uint st = base + woff + v - c;
    starts[cell]  = st;
    cursors[cell] = st;
    if (cell == NCELL - 1) starts[NCELL] = st + c;   // = 65536
}

__global__ __launch_bounds__(256) void cell_scatter(const int* __restrict__ coords,
                                                    uint* __restrict__ cursors,
                                                    uint2* __restrict__ sorted) {
    int i = blockIdx.x * 256 + threadIdx.x;
    int x = coords[3 * i + 0], y = coords[3 * i + 1], z = coords[3 * i + 2];
    int cell = (x >> 2) | ((y >> 2) << 5) | ((z >> 2) << 10);
    uint pos = atomicAdd(&cursors[cell], 1u);
    // packed for v_pk_sub_i16 / v_dot2: w0 = x | y<<16, w1 = idx | z<<16
    sorted[pos] = make_uint2((uint)(x | (y << 16)), (uint)(i | (z << 16)));
}

__global__ __launch_bounds__(256, 4) void knn_search(const uint* __restrict__ starts,
                                                     const uint2* __restrict__ sorted,
                                                     const float* __restrict__ feat,
                                                     float* __restrict__ out) {
    // XCD-chunked swizzle: consecutive logical blocks -> same XCD L2.
    int blk  = (blockIdx.x & 7) * 128 + (blockIdx.x >> 3);   // 1024 blocks
    int wave = threadIdx.x >> 6;                             // 4 waves/block
    int lane = threadIdx.x & 63;
    int qslot = lane & 15;                                   // 16 queries/wave
    int slice = lane >> 4;                                   // 4 slices/query
    int qpos = blk * 64 + wave * 16 + qslot;

    uint2 me = sorted[qpos];
    uint qxy = me.x;                       // qx | qy<<16
    uint qzp = me.y & 0xFFFF0000u;         // qz<<16
    uint qidx = me.y & 0xFFFFu;            // original index
    int qx = (int)(me.x & 0xFFFFu);
    int qy = (int)(me.x >> 16);
    int qz = (int)(me.y >> 16);
    int cx = qx >> 2, cy = qy >> 2, cz = qz >> 2;

    uint k[16];
#pragma unroll
    for (int j = 0; j < 16; ++j) k[j] = 0xFFFFFFFFu;

    auto insert1 = [&](uint2 pt) {
        short2v A = u2s(pt.x) - u2s(qxy);          // (dx, dy)
        short2v B = u2s(pt.y) - u2s(qzp);          // (idx, dz)
        uint Bu = s2u(B);
        short2v Bm = u2s(Bu & 0xFFFF0000u);        // (0, dz)
        int d2 = dot2acc(A, A, dot2acc(Bm, Bm, 0));
        uint key = ((uint)d2 << 16) + (Bu & 0xFFFFu);
        // in-place med3 insert: 15 independent ops (reads old j-1)
#pragma unroll
        for (int j = 15; j >= 1; --j)
            asm("v_med3_u32 %0, %1, %2, %3"
                : "=v"(k[j]) : "v"(k[j - 1]), "v"(k[j]), "v"(key));
        k[0] = min(k[0], key);
    };

    // sliced scan (stride 4 across slices) -- used only by the cold redo path
    auto scan4 = [&](uint p0, uint p1) {
        for (uint p = p0 + (uint)slice; p < p1; p += 4u) insert1(sorted[p]);
    };

    // bitonic min-half with partner lane (lane ^ mask): k becomes a bitonic
    // sequence holding the exact top-16 SET of the pair
    auto merge_min = [&](int mask) {
        uint b[16];
#pragma unroll
        for (int j = 0; j < 16; ++j) b[j] = __shfl_xor(k[j], mask, 64);
#pragma unroll
        for (int j = 0; j < 16; ++j) k[j] = min(k[j], b[15 - j]);
    };
    // bitonic cleanup: sorts the bitonic sequence ascending
    auto clean = [&]() {
#pragma unroll
        for (int d = 8; d >= 1; d >>= 1) {
#pragma unroll
            for (int i = 0; i < 16; ++i) {
                if ((i & d) == 0) {
                    uint lo = min(k[i], k[i + d]);
                    uint hi = max(k[i], k[i + d]);
                    k[i] = lo;
                    k[i + d] = hi;
                }
            }
        }
    };
    auto merge = [&](int mask) { merge_min(mask); clean(); };
    auto merge_all = [&]() { merge(16); merge(32); };

    // ---- quadrant-aligned 4x4x4 box, SHIFT-clamped (always full size) ----
    int xa = min(max(cx - ((qx & 3) < 2 ? 2 : 1), 0), 28);
    int ya = min(max(cy - ((qy & 3) < 2 ? 2 : 1), 0), 28);
    int za = min(max(cz - ((qz & 3) < 2 ? 2 : 1), 0), 28);

    // lane owns 4 whole rows: y = ya+slice, z = za+0..3. 4 streams, 2 pts
    // per stream per iteration via ONE 16-B load (pad entry in 'sorted'
    // keeps the tail read in-bounds; inserts predicated).
    {
        int ybase = (ya + slice) << 5;
        int rb0 = ybase | ((za + 0) << 10);
        int rb1 = ybase | ((za + 1) << 10);
        int rb2 = ybase | ((za + 2) << 10);
        int rb3 = ybase | ((za + 3) << 10);
        uint pA = starts[rb0 + xa], eA = starts[rb0 + xa + 4];
        uint pB = starts[rb1 + xa], eB = starts[rb1 + xa + 4];
        uint pC = starts[rb2 + xa], eC = starts[rb2 + xa + 4];
        uint pD = starts[rb3 + xa], eD = starts[rb3 + xa + 4];
        while (__any((pA < eA) || (pB < eB) || (pC < eC) || (pD < eD))) {
            bool a0 = pA < eA, a1 = pA + 1 < eA;
            bool b0 = pB < eB, b1 = pB + 1 < eB;
            bool c0 = pC < eC, c1 = pC + 1 < eC;
            bool d0 = pD < eD, d1 = pD + 1 < eD;
            u32x4 VA, VB, VC, VD;
            if (a0) VA = *reinterpret_cast<const u32x4*>(sorted + pA);
            if (b0) VB = *reinterpret_cast<const u32x4*>(sorted + pB);
            if (c0) VC = *reinterpret_cast<const u32x4*>(sorted + pC);
            if (d0) VD = *reinterpret_cast<const u32x4*>(sorted + pD);
            pA += (a0 ? 1u : 0u) + (a1 ? 1u : 0u);
            pB += (b0 ? 1u : 0u) + (b1 ? 1u : 0u);
            pC += (c0 ? 1u : 0u) + (c1 ? 1u : 0u);
            pD += (d0 ? 1u : 0u) + (d1 ? 1u : 0u);
            if (a0) insert1(make_uint2(VA.x, VA.y));
            if (b0) insert1(make_uint2(VB.x, VB.y));
            if (c0) insert1(make_uint2(VC.x, VC.y));
            if (d0) insert1(make_uint2(VD.x, VD.y));
            if (a1) insert1(make_uint2(VA.z, VA.w));
            if (b1) insert1(make_uint2(VB.z, VB.w));
            if (c1) insert1(make_uint2(VC.z, VC.w));
            if (d1) insert1(make_uint2(VD.z, VD.w));
        }
    }
    // exact top-16 SET over the box (final merge leaves k bitonic-unsorted;
    // the gather is a set-sum so order is irrelevant on the hot path)
    merge(16); merge_min(32);
    uint mx = k[0];
#pragma unroll
    for (int j = 1; j < 16; ++j) mx = max(mx, k[j]);

    // ---- cold redo: uncovered space has min-d2 >= 49 (P ~ 1e-7/query) ----
    bool redo = (mx >> 16) >= 49u;
    if (__any(redo)) {
        clean();   // restore sorted order: merge machinery needs sorted inputs
        // triggered queries: discard everything, rescan from scratch (sliced).
        // others: keep slice 0 only (slices!=0 must reset before re-merge).
        if (redo || slice != 0) {
#pragma unroll
            for (int j = 0; j < 16; ++j) k[j] = 0xFFFFFFFFu;
        }
        if (redo) {
            int xl = max(cx - 2, 0), xh = min(cx + 2, 31);
            int yl = max(cy - 2, 0), yh = min(cy + 2, 31);
            int zl = max(cz - 2, 0), zh = min(cz + 2, 31);
            for (int z = zl; z <= zh; ++z)
                for (int y = yl; y <= yh; ++y) {
                    int rb = (y << 5) | (z << 10);
                    scan4(starts[rb + xl], starts[rb + xh + 1]);
                }
        }
        merge_all();
        for (int r = 3; r < 32; ++r) {
            uint b = (uint)(4 * r - 3);
            bool active = (k[15] >> 16) >= b * b;
            if (!__any(active)) break;
            if (slice != 0) {
#pragma unroll
                for (int j = 0; j < 16; ++j) k[j] = 0xFFFFFFFFu;
            }
            if (active) {
                int z0 = cz - r < 0 ? 0 : cz - r;
                int z1 = cz + r > 31 ? 31 : cz + r;
                for (int z = z0; z <= z1; ++z) {
                    bool zface = (z == cz - r) || (z == cz + r);
                    int y0 = cy - r < 0 ? 0 : cy - r;
                    int y1 = cy + r > 31 ? 31 : cy + r;
                    for (int y = y0; y <= y1; ++y) {
                        bool face = zface || (y == cy - r) || (y == cy + r);
                        int rb = (y << 5) | (z << 10);
                        if (face) {
                            int x0 = cx - r < 0 ? 0 : cx - r;
                            int x1 = cx + r > 31 ? 31 : cx + r;
                            scan4(starts[rb + x0], starts[rb + x1 + 1]);
                        } else {
                            int xL = cx - r;
                            if (xL >= 0) scan4(starts[rb + xL], starts[rb + xL + 1]);
                            int xR = cx + r;
                            if (xR <= 31) scan4(starts[rb + xR], starts[rb + xR + 1]);
                        }
                    }
                }
            }
            merge_all();
        }
    }

    // ---- fused gather: float4 channels, 4 passes x 4 queries ----
    uint ki[16];
#pragma unroll
    for (int j = 0; j < 16; ++j) ki[j] = k[j] & 0xFFFFu;

    int ch = lane & 15;          // float4 channel group (4 channels)
    int qg = lane >> 4;          // query within pass
#pragma unroll
    for (int p = 0; p < 4; ++p) {
        int qs = p * 4 + qg;     // query slot 0..15; lane qs holds it (slice 0)
        uint qorig = __shfl(qidx, qs, 64);
        float4 acc = make_float4(0.f, 0.f, 0.f, 0.f);
#pragma unroll
        for (int j = 0; j < 16; ++j) {
            uint nj = __shfl(ki[j], qs, 64);
            float4 v = reinterpret_cast<const float4*>(feat)[nj * 16u + (uint)ch];
            acc.x += v.x; acc.y += v.y; acc.z += v.z; acc.w += v.w;
        }
        reinterpret_cast<float4*>(out)[qorig * 16u + (uint)ch] = acc;
    }
}

extern "C" void kernel_launch(void* const* d_in, const int* in_sizes, int n_in,
                              void* d_out, int out_size, void* d_ws, size_t ws_size,
                              hipStream_t stream) {
    const int*   coords = (const int*)d_in[0];
    const float* feat   = (const float*)d_in[1];
    float*       out    = (float*)d_out;

    uint* W = (uint*)d_ws;
    uint*  counts  = W;                       // 32768, memset-zeroed
    uint*  starts  = W + 32768;               // 32769
    uint*  cursors = W + 65540;               // 32768 (16B aligned)
    uint2* sorted  = (uint2*)(W + 98308);     // 65536 entries + 1 pad (16B reads)

    hipMemsetAsync(counts, 0, NCELL * sizeof(uint), stream);
    cell_count<<<NPTS / 256, 256, 0, stream>>>(coords, counts);
    scan_fused<<<NCELL / 256, 256, 0, stream>>>(counts, starts, cursors);
    cell_scatter<<<NPTS / 256, 256, 0, stream>>>(coords, cursors, sorted);
    knn_search<<<1024, 256, 0, stream>>>(starts, sorted, feat, out);
}

// Round 12
// 61.597 us; speedup vs baseline: 3.6530x; 1.2137x over previous
//
#include <hip/hip_runtime.h>

// Exact KNN (faiss-equivalent, (dist,idx)-lexicographic ties) + fused neighbor
// feature sum. N=65536 pts on 128^3 int grid, K=16, C=64.
//
// Cells = 4^3 coords -> 32^3 = 32768 cells, ~2 pts/cell. Key = (d2<<16)|idx
// (d2 <= 48387 < 2^16): unsigned order == (dist, idx) lexicographic.
//
// PROLOGUE lessons:
//  r1-r3: grid barriers ~8us each on MI355X (any poll discipline) -> none.
//  r5:    same-address atomic multiplicity must stay < ~100 (~100ns/RMW).
//  r11:   scan_fused's serial base-reduce loop (127 dependent L2 loads in
//         block 127) cost ~13us -- a dispatch boundary (~1.5us) is CHEAPER
//         than a serial latency chain. Reverted to the proven two-dispatch
//         chunk_reduce + scan_chunk (61.5us total, measured r4/r6/r7).
//  r12:   coords loaded as int3 (one dwordx3 address) in count/scatter
//         instead of 3 scalar loads (3x fewer lane-addresses).
//
// KNN lessons (r0-r10):
//  - fused kernel pinned ~42us across 8 configs varying VALU +-50%, waves
//    2x, load width 2x: VMEM-issue bound; scan & gather waves OVERLAP
//    inside the fused kernel (~max, not sum).
//  - r8 LDS-staged per-lane scan: 82us (divergent ds chains, 2 blk/CU).
//  - r9 RULE #20: runtime-indexed private k[] -> demoted to LDS, 161us.
//  - r10 search/gather split: 97.8us -- splitting destroys the overlap.
//
// knn_search: wave = 16 queries x 4 slices; lane owns 4 whole rows
// (y = ya+slice, z = za+0..3); 4 streams x 2 pts/iter (one 16-B load each).
// Main scan = quadrant-aligned 4x4x4 cell box, SHIFT-clamped to the grid
// (origin clamp [0,28]) so the box is always full 4x4x4. Guarantee:
// uncovered min-d2 >= 49. Per-lane sorted top-16 via med3 insert network.
// Merge tree depth 2 (masks 16,32); FINAL merge keeps only the min-half
// (bitonic, unsorted) since the gather is a set-sum; redo bound via
// max-tree; cold redo (P~1e-7/query) re-sorts, then cube r<=2 + Chebyshev
// shells r>=3 ((4r-3)^2 bound), exact.
// Gather fused: lane = 4 channels x 16 lanes/query, 4 passes x 4 queries;
// float4 feature-row loads; output written directly.

typedef unsigned int uint;
typedef unsigned short ushort;
typedef short short2v __attribute__((ext_vector_type(2)));
typedef uint u32x4 __attribute__((ext_vector_type(4), aligned(8)));

#define NPTS   65536
#define NCELL  32768

static __device__ inline short2v u2s(uint v) { union { uint u; short2v s; } c; c.u = v; return c.s; }
static __device__ inline uint s2u(short2v v) { union { uint u; short2v s; } c; c.s = v; return c.u; }

static __device__ inline int dot2acc(short2v a, short2v b, int c) {
#if __has_builtin(__builtin_amdgcn_sdot2)
    return __builtin_amdgcn_sdot2(a, b, c, false);
#else
    return (int)a.x * (int)b.x + (int)a.y * (int)b.y + c;
#endif
}

__global__ __launch_bounds__(256) void cell_count(const int* __restrict__ coords,
                                                  uint* __restrict__ counts) {
    int i = blockIdx.x * 256 + threadIdx.x;
    int3 v = reinterpret_cast<const int3*>(coords)[i];   // one dwordx3 address
    int cell = (v.x >> 2) | ((v.y >> 2) << 5) | ((v.z >> 2) << 10);
    atomicAdd(&counts[cell], 1u);
}

// Contention-free chunk totals: block j reduces its 256 counts (coalesced),
// one plain store. No atomics. (Parallel across 128 blocks -- r11 lesson:
// do NOT serialize this into per-block prefix loops.)
__global__ __launch_bounds__(256) void chunk_reduce(const uint* __restrict__ counts,
                                                    uint* __restrict__ chunktot) {
    __shared__ uint wsum[4];
    int tid = threadIdx.x;
    int lane = tid & 63, wv = tid >> 6;
    uint c = counts[blockIdx.x * 256 + tid];
#pragma unroll
    for (int off = 32; off; off >>= 1) c += __shfl_xor(c, off, 64);
    if (lane == 0) wsum[wv] = c;
    __syncthreads();
    if (tid == 0) chunktot[blockIdx.x] = wsum[0] + wsum[1] + wsum[2] + wsum[3];
}

// Deterministic cell-ordered scan, no grid barrier: chunk base = reduce of
// chunktot[0..chunk) (15 wave ops), + block-local scan of 256 cells.
__global__ __launch_bounds__(256) void scan_chunk(const uint* __restrict__ counts,
                                                  const uint* __restrict__ chunktot,
                                                  uint* __restrict__ starts,
                                                  uint* __restrict__ cursors) {
    __shared__ uint wsum[4];
    int b = blockIdx.x;                  // chunk id, 0..127
    int tid = threadIdx.x;
    int lane = tid & 63, wv = tid >> 6;
    int cell = b * 256 + tid;

    uint t0 = chunktot[lane];
    uint t1 = chunktot[64 + lane];
    uint s = (lane < b ? t0 : 0u) + (64 + lane < b ? t1 : 0u);
#pragma unroll
    for (int off = 32; off; off >>= 1) s += __shfl_xor(s, off, 64);
    uint base = s;

    uint c = counts[cell];
    uint v = c;
#pragma unroll
    for (int off = 1; off < 64; off <<= 1) {
        uint u = __shfl_up(v, off, 64);
        if (lane >= off) v += u;
    }
    if (lane == 63) wsum[wv] = v;
    __syncthreads();
    uint woff = 0;
#pragma unroll
    for (int j = 0; j < 4; ++j) woff += (j < wv) ? wsum[j] : 0u;
    uint st = base + woff + v - c;
    starts[cell]  = st;
    cursors[cell] = st;
    if (cell == NCELL - 1) starts[NCELL] = st + c;   // = 65536
}

__global__ __launch_bounds__(256) void cell_scatter(const int* __restrict__ coords,
                                                    uint* __restrict__ cursors,
                                                    uint2* __restrict__ sorted) {
    int i = blockIdx.x * 256 + threadIdx.x;
    int3 v = reinterpret_cast<const int3*>(coords)[i];   // one dwordx3 address
    int cell = (v.x >> 2) | ((v.y >> 2) << 5) | ((v.z >> 2) << 10);
    uint pos = atomicAdd(&cursors[cell], 1u);
    // packed for v_pk_sub_i16 / v_dot2: w0 = x | y<<16, w1 = idx | z<<16
    sorted[pos] = make_uint2((uint)(v.x | (v.y << 16)), (uint)(i | (v.z << 16)));
}

__global__ __launch_bounds__(256, 4) void knn_search(const uint* __restrict__ starts,
                                                     const uint2* __restrict__ sorted,
                                                     const float* __restrict__ feat,
                                                     float* __restrict__ out) {
    // XCD-chunked swizzle: consecutive logical blocks -> same XCD L2.
    int blk  = (blockIdx.x & 7) * 128 + (blockIdx.x >> 3);   // 1024 blocks
    int wave = threadIdx.x >> 6;                             // 4 waves/block
    int lane = threadIdx.x & 63;
    int qslot = lane & 15;                                   // 16 queries/wave
    int slice = lane >> 4;                                   // 4 slices/query
    int qpos = blk * 64 + wave * 16 + qslot;

    uint2 me = sorted[qpos];
    uint qxy = me.x;                       // qx | qy<<16
    uint qzp = me.y & 0xFFFF0000u;         // qz<<16
    uint qidx = me.y & 0xFFFFu;            // original index
    int qx = (int)(me.x & 0xFFFFu);
    int qy = (int)(me.x >> 16);
    int qz = (int)(me.y >> 16);
    int cx = qx >> 2, cy = qy >> 2, cz = qz >> 2;

    uint k[16];
#pragma unroll
    for (int j = 0; j < 16; ++j) k[j] = 0xFFFFFFFFu;

    auto insert1 = [&](uint2 pt) {
        short2v A = u2s(pt.x) - u2s(qxy);          // (dx, dy)
        short2v B = u2s(pt.y) - u2s(qzp);          // (idx, dz)
        uint Bu = s2u(B);
        short2v Bm = u2s(Bu & 0xFFFF0000u);        // (0, dz)
        int d2 = dot2acc(A, A, dot2acc(Bm, Bm, 0));
        uint key = ((uint)d2 << 16) + (Bu & 0xFFFFu);
        // in-place med3 insert: 15 independent ops (reads old j-1)
#pragma unroll
        for (int j = 15; j >= 1; --j)
            asm("v_med3_u32 %0, %1, %2, %3"
                : "=v"(k[j]) : "v"(k[j - 1]), "v"(k[j]), "v"(key));
        k[0] = min(k[0], key);
    };

    // sliced scan (stride 4 across slices) -- used only by the cold redo path
    auto scan4 = [&](uint p0, uint p1) {
        for (uint p = p0 + (uint)slice; p < p1; p += 4u) insert1(sorted[p]);
    };

    // bitonic min-half with partner lane (lane ^ mask): k becomes a bitonic
    // sequence holding the exact top-16 SET of the pair
    auto merge_min = [&](int mask) {
        uint b[16];
#pragma unroll
        for (int j = 0; j < 16; ++j) b[j] = __shfl_xor(k[j], mask, 64);
#pragma unroll
        for (int j = 0; j < 16; ++j) k[j] = min(k[j], b[15 - j]);
    };
    // bitonic cleanup: sorts the bitonic sequence ascending
    auto clean = [&]() {
#pragma unroll
        for (int d = 8; d >= 1; d >>= 1) {
#pragma unroll
            for (int i = 0; i < 16; ++i) {
                if ((i & d) == 0) {
                    uint lo = min(k[i], k[i + d]);
                    uint hi = max(k[i], k[i + d]);
                    k[i] = lo;
                    k[i + d] = hi;
                }
            }
        }
    };
    auto merge = [&](int mask) { merge_min(mask); clean(); };
    auto merge_all = [&]() { merge(16); merge(32); };

    // ---- quadrant-aligned 4x4x4 box, SHIFT-clamped (always full size) ----
    int xa = min(max(cx - ((qx & 3) < 2 ? 2 : 1), 0), 28);
    int ya = min(max(cy - ((qy & 3) < 2 ? 2 : 1), 0), 28);
    int za = min(max(cz - ((qz & 3) < 2 ? 2 : 1), 0), 28);

    // lane owns 4 whole rows: y = ya+slice, z = za+0..3. 4 streams, 2 pts
    // per stream per iteration via ONE 16-B load (pad entry in 'sorted'
    // keeps the tail read in-bounds; inserts predicated).
    {
        int ybase = (ya + slice) << 5;
        int rb0 = ybase | ((za + 0) << 10);
        int rb1 = ybase | ((za + 1) << 10);
        int rb2 = ybase | ((za + 2) << 10);
        int rb3 = ybase | ((za + 3) << 10);
        uint pA = starts[rb0 + xa], eA = starts[rb0 + xa + 4];
        uint pB = starts[rb1 + xa], eB = starts[rb1 + xa + 4];
        uint pC = starts[rb2 + xa], eC = starts[rb2 + xa + 4];
        uint pD = starts[rb3 + xa], eD = starts[rb3 + xa + 4];
        while (__any((pA < eA) || (pB < eB) || (pC < eC) || (pD < eD))) {
            bool a0 = pA < eA, a1 = pA + 1 < eA;
            bool b0 = pB < eB, b1 = pB + 1 < eB;
            bool c0 = pC < eC, c1 = pC + 1 < eC;
            bool d0 = pD < eD, d1 = pD + 1 < eD;
            u32x4 VA, VB, VC, VD;
            if (a0) VA = *reinterpret_cast<const u32x4*>(sorted + pA);
            if (b0) VB = *reinterpret_cast<const u32x4*>(sorted + pB);
            if (c0) VC = *reinterpret_cast<const u32x4*>(sorted + pC);
            if (d0) VD = *reinterpret_cast<const u32x4*>(sorted + pD);
            pA += (a0 ? 1u : 0u) + (a1 ? 1u : 0u);
            pB += (b0 ? 1u : 0u) + (b1 ? 1u : 0u);
            pC += (c0 ? 1u : 0u) + (c1 ? 1u : 0u);
            pD += (d0 ? 1u : 0u) + (d1 ? 1u : 0u);
            if (a0) insert1(make_uint2(VA.x, VA.y));
            if (b0) insert1(make_uint2(VB.x, VB.y));
            if (c0) insert1(make_uint2(VC.x, VC.y));
            if (d0) insert1(make_uint2(VD.x, VD.y));
            if (a1) insert1(make_uint2(VA.z, VA.w));
            if (b1) insert1(make_uint2(VB.z, VB.w));
            if (c1) insert1(make_uint2(VC.z, VC.w));
            if (d1) insert1(make_uint2(VD.z, VD.w));
        }
    }
    // exact top-16 SET over the box (final merge leaves k bitonic-unsorted;
    // the gather is a set-sum so order is irrelevant on the hot path)
    merge(16); merge_min(32);
    uint mx = k[0];
#pragma unroll
    for (int j = 1; j < 16; ++j) mx = max(mx, k[j]);

    // ---- cold redo: uncovered space has min-d2 >= 49 (P ~ 1e-7/query) ----
    bool redo = (mx >> 16) >= 49u;
    if (__any(redo)) {
        clean();   // restore sorted order: merge machinery needs sorted inputs
        // triggered queries: discard everything, rescan from scratch (sliced).
        // others: keep slice 0 only (slices!=0 must reset before re-merge).
        if (redo || slice != 0) {
#pragma unroll
            for (int j = 0; j < 16; ++j) k[j] = 0xFFFFFFFFu;
        }
        if (redo) {
            int xl = max(cx - 2, 0), xh = min(cx + 2, 31);
            int yl = max(cy - 2, 0), yh = min(cy + 2, 31);
            int zl = max(cz - 2, 0), zh = min(cz + 2, 31);
            for (int z = zl; z <= zh; ++z)
                for (int y = yl; y <= yh; ++y) {
                    int rb = (y << 5) | (z << 10);
                    scan4(starts[rb + xl], starts[rb + xh + 1]);
                }
        }
        merge_all();
        for (int r = 3; r < 32; ++r) {
            uint b = (uint)(4 * r - 3);
            bool active = (k[15] >> 16) >= b * b;
            if (!__any(active)) break;
            if (slice != 0) {
#pragma unroll
                for (int j = 0; j < 16; ++j) k[j] = 0xFFFFFFFFu;
            }
            if (active) {
                int z0 = cz - r < 0 ? 0 : cz - r;
                int z1 = cz + r > 31 ? 31 : cz + r;
                for (int z = z0; z <= z1; ++z) {
                    bool zface = (z == cz - r) || (z == cz + r);
                    int y0 = cy - r < 0 ? 0 : cy - r;
                    int y1 = cy + r > 31 ? 31 : cy + r;
                    for (int y = y0; y <= y1; ++y) {
                        bool face = zface || (y == cy - r) || (y == cy + r);
                        int rb = (y << 5) | (z << 10);
                        if (face) {
                            int x0 = cx - r < 0 ? 0 : cx - r;
                            int x1 = cx + r > 31 ? 31 : cx + r;
                            scan4(starts[rb + x0], starts[rb + x1 + 1]);
                        } else {
                            int xL = cx - r;
                            if (xL >= 0) scan4(starts[rb + xL], starts[rb + xL + 1]);
                            int xR = cx + r;
                            if (xR <= 31) scan4(starts[rb + xR], starts[rb + xR + 1]);
                        }
                    }
                }
            }
            merge_all();
        }
    }

    // ---- fused gather: float4 channels, 4 passes x 4 queries ----
    uint ki[16];
#pragma unroll
    for (int j = 0; j < 16; ++j) ki[j] = k[j] & 0xFFFFu;

    int ch = lane & 15;          // float4 channel group (4 channels)
    int qg = lane >> 4;          // query within pass
#pragma unroll
    for (int p = 0; p < 4; ++p) {
        int qs = p * 4 + qg;     // query slot 0..15; lane qs holds it (slice 0)
        uint qorig = __shfl(qidx, qs, 64);
        float4 acc = make_float4(0.f, 0.f, 0.f, 0.f);
#pragma unroll
        for (int j = 0; j < 16; ++j) {
            uint nj = __shfl(ki[j], qs, 64);
            float4 v = reinterpret_cast<const float4*>(feat)[nj * 16u + (uint)ch];
            acc.x += v.x; acc.y += v.y; acc.z += v.z; acc.w += v.w;
        }
        reinterpret_cast<float4*>(out)[qorig * 16u + (uint)ch] = acc;
    }
}

extern "C" void kernel_launch(void* const* d_in, const int* in_sizes, int n_in,
                              void* d_out, int out_size, void* d_ws, size_t ws_size,
                              hipStream_t stream) {
    const int*   coords = (const int*)d_in[0];
    const float* feat   = (const float*)d_in[1];
    float*       out    = (float*)d_out;

    uint* W = (uint*)d_ws;
    uint*  chunktot = W;                      // 128 (written by chunk_reduce)
    uint*  counts   = W + 128;                // 32768, memset-zeroed
    uint*  starts   = W + 32896;              // 32769
    uint*  cursors  = W + 65668;              // 32768 (16B aligned)
    uint2* sorted   = (uint2*)(W + 98436);    // 65536 entries + 1 pad (16B reads)

    hipMemsetAsync(counts, 0, NCELL * sizeof(uint), stream);
    cell_count<<<NPTS / 256, 256, 0, stream>>>(coords, counts);
    chunk_reduce<<<NCELL / 256, 256, 0, stream>>>(counts, chunktot);
    scan_chunk<<<NCELL / 256, 256, 0, stream>>>(counts, chunktot, starts, cursors);
    cell_scatter<<<NPTS / 256, 256, 0, stream>>>(coords, cursors, sorted);
    knn_search<<<1024, 256, 0, stream>>>(starts, sorted, feat, out);
}